// Round 1
// baseline (1011.718 us; speedup 1.0000x reference)
//
#include <hip/hip_runtime.h>

// Wide & Deep forward, MI355X.
// K1: gather embeddings + 2-layer MLP -> h2 (4096x128) bf16 into d_ws.
// K2: fused head: out = sigmoid(h2 @ Wd^T + wide_gather + b_head), 128x128 MFMA tiles.

#define BATCH    4096
#define NITEMS   10000
#define HEADCOLS 10128   // 10000 one-hot + 128 dense
#define DENSEOFF 10000

typedef __attribute__((ext_vector_type(8))) short short8;
typedef __attribute__((ext_vector_type(4))) short short4v;
typedef __attribute__((ext_vector_type(4))) float floatx4;

__device__ inline unsigned short f2bf(float f) {
    unsigned u = __builtin_bit_cast(unsigned, f);
    unsigned r = (u + 0x7FFFu + ((u >> 16) & 1u)) >> 16;
    return (unsigned short)r;
}

// ---------------- K1: embeddings + MLP -> h2 (bf16) ----------------
// 128 blocks x 256 threads; each block handles 32 batch rows.
__global__ __launch_bounds__(256) void k1_mlp(
    const int* __restrict__ inter,
    const float* __restrict__ U, const float* __restrict__ I,
    const float* __restrict__ w1, const float* __restrict__ b1,
    const float* __restrict__ w2, const float* __restrict__ b2,
    unsigned short* __restrict__ h2b)
{
    __shared__ float e_lds[32 * 64];
    __shared__ float h1_lds[32 * 128];
    const int t  = threadIdx.x;
    const int b0 = blockIdx.x * 32;

    // stage concat(user_emb, item_emb): 32 rows x 64
    for (int idx = t; idx < 32 * 64; idx += 256) {
        int b = idx >> 6, d = idx & 63;
        int u  = inter[2 * (b0 + b)];
        int it = inter[2 * (b0 + b) + 1];
        e_lds[idx] = (d < 32) ? U[(long)u * 32 + d] : I[(long)it * 32 + (d - 32)];
    }
    __syncthreads();

    // layer 1: h1[b][i] = relu(w1[i,:] . e[b,:] + b1[i])
    {
        const int i  = t & 127;
        const int bh = (t >> 7) * 16;      // 2 half-groups x 16 rows
        float acc[16];
        #pragma unroll
        for (int b = 0; b < 16; b++) acc[b] = b1[i];
        for (int d = 0; d < 64; d += 4) {
            float4 w = *(const float4*)&w1[i * 64 + d];
            #pragma unroll
            for (int b = 0; b < 16; b++) {
                const float* e = &e_lds[(bh + b) * 64 + d];  // LDS broadcast
                acc[b] += w.x * e[0] + w.y * e[1] + w.z * e[2] + w.w * e[3];
            }
        }
        #pragma unroll
        for (int b = 0; b < 16; b++) h1_lds[(bh + b) * 128 + i] = fmaxf(acc[b], 0.f);
    }
    __syncthreads();

    // layer 2: h2[b][o] = relu(w2[o,:] . h1[b,:] + b2[o]) -> bf16
    {
        const int o  = t & 127;
        const int bh = (t >> 7) * 16;
        float acc[16];
        #pragma unroll
        for (int b = 0; b < 16; b++) acc[b] = b2[o];
        for (int k = 0; k < 128; k += 4) {
            float4 w = *(const float4*)&w2[o * 128 + k];
            #pragma unroll
            for (int b = 0; b < 16; b++) {
                const float* h = &h1_lds[(bh + b) * 128 + k];  // LDS broadcast
                acc[b] += w.x * h[0] + w.y * h[1] + w.z * h[2] + w.w * h[3];
            }
        }
        #pragma unroll
        for (int b = 0; b < 16; b++)
            h2b[(long)(b0 + bh + b) * 128 + o] = f2bf(fmaxf(acc[b], 0.f));
    }
}

// ---------------- K2: fused head ----------------
// Tile 128(b) x 128(j), 4 waves (2x2), 16x16x32 bf16 MFMA, K=128 in one shot.
#define LDSTR 136   // 128 + 8 bf16 pad (16B-aligned rows, 2-way-max bank aliasing)

__global__ __launch_bounds__(256) void k2_head(
    const unsigned short* __restrict__ h2b,
    const float* __restrict__ w_head, const float* __restrict__ b_head,
    const int* __restrict__ inter, float* __restrict__ out)
{
    __shared__ short A_lds[128 * LDSTR];
    __shared__ short B_lds[128 * LDSTR];
    __shared__ int items[128];

    const int t     = threadIdx.x;
    const int bbase = blockIdx.x * 128;   // b-tiles fast -> adjacent blocks share j-tile (L2/L3 reuse of w_head rows)
    const int jbase = blockIdx.y * 128;

    if (t < 128) items[t] = inter[2 * (bbase + t) + 1];

    // stage A: h2 tile (128 x 128 bf16), 16B chunks
    for (int idx = t; idx < 128 * 16; idx += 256) {
        int r = idx >> 4, s = idx & 15;
        short8 v = *(const short8*)&h2b[(long)(bbase + r) * 128 + s * 8];
        *(short8*)&A_lds[r * LDSTR + s * 8] = v;
    }
    // stage B: dense cols of w_head (128 x 128), f32 -> bf16
    for (int idx = t; idx < 128 * 32; idx += 256) {
        int r = idx >> 5, s = idx & 31;
        int j = jbase + r;
        short4v o4;
        if (j < NITEMS) {
            float4 w = *(const float4*)&w_head[(long)j * HEADCOLS + DENSEOFF + s * 4];
            o4[0] = (short)f2bf(w.x); o4[1] = (short)f2bf(w.y);
            o4[2] = (short)f2bf(w.z); o4[3] = (short)f2bf(w.w);
        } else {
            o4[0] = 0; o4[1] = 0; o4[2] = 0; o4[3] = 0;
        }
        *(short4v*)&B_lds[r * LDSTR + s * 4] = o4;
    }
    __syncthreads();

    const int lane = t & 63, wave = t >> 6;
    const int wb = (wave & 1) * 64, wj = (wave >> 1) * 64;
    const int col = lane & 15, quad = lane >> 4;

    floatx4 acc[4][4];
    #pragma unroll
    for (int bi = 0; bi < 4; bi++)
        #pragma unroll
        for (int ji = 0; ji < 4; ji++)
            #pragma unroll
            for (int r = 0; r < 4; r++) acc[bi][ji][r] = 0.f;

    // K = 128 = 4 x 32
    #pragma unroll
    for (int ks = 0; ks < 4; ks++) {
        short8 a[4], b[4];
        #pragma unroll
        for (int bi = 0; bi < 4; bi++)
            a[bi] = *(const short8*)&A_lds[(wb + bi * 16 + col) * LDSTR + ks * 32 + quad * 8];
        #pragma unroll
        for (int ji = 0; ji < 4; ji++)
            b[ji] = *(const short8*)&B_lds[(wj + ji * 16 + col) * LDSTR + ks * 32 + quad * 8];
        #pragma unroll
        for (int bi = 0; bi < 4; bi++)
            #pragma unroll
            for (int ji = 0; ji < 4; ji++)
                acc[bi][ji] = __builtin_amdgcn_mfma_f32_16x16x32_bf16(a[bi], b[ji], acc[bi][ji], 0, 0, 0);
    }

    // epilogue: + bias + wide gather, sigmoid, store.
    // C/D layout: col = lane&15, row = quad*4 + reg  (m89-verified)
    #pragma unroll
    for (int ji = 0; ji < 4; ji++) {
        int j = jbase + wj + ji * 16 + col;
        bool jv = (j < NITEMS);
        float bias = jv ? b_head[j] : 0.f;
        const float* wrow = w_head + (long)(jv ? j : 0) * HEADCOLS;
        #pragma unroll
        for (int bi = 0; bi < 4; bi++) {
            #pragma unroll
            for (int r = 0; r < 4; r++) {
                int bl = wb + bi * 16 + quad * 4 + r;
                float wide = jv ? wrow[items[bl]] : 0.f;   // scattered 4B load, L2-resident row
                float x = acc[bi][ji][r] + bias + wide;
                float y = 1.f / (1.f + __expf(-x));
                if (jv) out[(long)(bbase + bl) * NITEMS + j] = y;
            }
        }
    }
}

extern "C" void kernel_launch(void* const* d_in, const int* in_sizes, int n_in,
                              void* d_out, int out_size, void* d_ws, size_t ws_size,
                              hipStream_t stream) {
    const int*   inter = (const int*)d_in[0];
    const float* U     = (const float*)d_in[1];
    const float* I     = (const float*)d_in[2];
    const float* w1    = (const float*)d_in[3];
    const float* b1    = (const float*)d_in[4];
    const float* w2    = (const float*)d_in[5];
    const float* b2    = (const float*)d_in[6];
    const float* wh    = (const float*)d_in[7];
    const float* bh    = (const float*)d_in[8];
    float* out = (float*)d_out;
    unsigned short* h2b = (unsigned short*)d_ws;   // 4096*128 bf16 = 1 MB

    k1_mlp<<<128, 256, 0, stream>>>(inter, U, I, w1, b1, w2, b2, h2b);
    k2_head<<<dim3(32, 79), 256, 0, stream>>>(h2b, wh, bh, inter, out);
}